// Round 1
// baseline (614.004 us; speedup 1.0000x reference)
//
#include <hip/hip_runtime.h>

#define NLAT 255
#define NLON 256
#define NPIX 49152
#define LMAX 255
#define MMAX 129
#define MCS  (2*MMAX)   // 258
// f intermediate layout: f[m][k][bc2], bc2 = n*256 + bc, k-stride 512 floats.

__global__ __launch_bounds__(256) void stageA(
    const float* __restrict__ x, const int* __restrict__ ring_index,
    const float* __restrict__ ring_mask, const float* __restrict__ phase,
    float* __restrict__ f)
{
    const int k       = blockIdx.x;        // ring
    const int bctile  = blockIdx.y * 64;   // bc base
    const int mcstile = blockIdx.z * 64;   // mcs base (even)
    const int t  = threadIdx.x;
    const int tx = t & 15, ty = t >> 4;

    __shared__ __align__(16) float Rs[16][65];   // [p][bc_local]
    __shared__ __align__(16) float Ts[16][68];   // [p][mcs_local]

    float acc[4][4];
#pragma unroll
    for (int j = 0; j < 4; ++j)
#pragma unroll
        for (int i = 0; i < 4; ++i) acc[j][i] = 0.f;

    for (int pc = 0; pc < NLON; pc += 16) {
        // ---- load ring chunk (gather from x), coalesced in p ----
        {
            int p   = pc + (t & 15);
            int idx = ring_index[k * NLON + p];
            float msk = ring_mask[k * NLON + p];
            float v = x[(size_t)(bctile + (t >> 4)) * NPIX + idx] * msk;
            Rs[t & 15][t >> 4] = v;
#pragma unroll
            for (int it = 1; it < 4; ++it) {
                int bcl = (t >> 4) + it * 16;
                Rs[t & 15][bcl] = x[(size_t)(bctile + bcl) * NPIX + idx] * msk;
            }
        }
        // ---- trig chunk: Ts[p][2*mm] = cos, Ts[p][2*mm+1] = -sin ----
        {
#pragma unroll
            for (int it = 0; it < 2; ++it) {
                int id = t + it * 256;       // 0..511
                int pl = id >> 5;            // 0..15
                int mm = id & 31;            // 0..31
                int m  = (mcstile >> 1) + mm;
                float s = 0.f, c = 0.f;
                if (m < MMAX) {
                    float ang = phase[k * NLON + pc + pl] * (float)m;
                    __sincosf(ang, &s, &c);
                }
                Ts[pl][mm * 2]     = c;
                Ts[pl][mm * 2 + 1] = -s;
            }
        }
        __syncthreads();
#pragma unroll
        for (int pp = 0; pp < 16; ++pp) {
            float a[4], b[4];
#pragma unroll
            for (int i = 0; i < 4; ++i) a[i] = Rs[pp][i * 16 + tx];
            const float4 bv = *(const float4*)&Ts[pp][ty * 4];
            b[0] = bv.x; b[1] = bv.y; b[2] = bv.z; b[3] = bv.w;
#pragma unroll
            for (int j = 0; j < 4; ++j)
#pragma unroll
                for (int i = 0; i < 4; ++i)
                    acc[j][i] += a[i] * b[j];
        }
        __syncthreads();
    }
    // ---- write f[m][k][bc2]: contiguous in bc per (j) -> coalesced ----
#pragma unroll
    for (int j = 0; j < 4; ++j) {
        int mcs = mcstile + ty * 4 + j;
        if (mcs < MCS) {
            int m = mcs >> 1, n = mcs & 1;
            size_t base = ((size_t)m * NLAT + k) * 512 + n * 256 + bctile;
#pragma unroll
            for (int i = 0; i < 4; ++i)
                f[base + i * 16 + tx] = acc[j][i];
        }
    }
}

__global__ __launch_bounds__(256) void stageB(
    const float* __restrict__ f, const float* __restrict__ pct,
    const float* __restrict__ w, float* __restrict__ out)
{
    const int m       = blockIdx.x;
    const int bc2tile = blockIdx.y * 64;
    const int ltile   = blockIdx.z * 64;
    const int t  = threadIdx.x;
    const int tx = t & 15, ty = t >> 4;

    __shared__ __align__(16) float Fs[16][65];   // [k_local][bc2_local]
    __shared__ __align__(16) float Ws[16][68];   // [k_local][l_local]

    float acc[4][4];
#pragma unroll
    for (int j = 0; j < 4; ++j)
#pragma unroll
        for (int i = 0; i < 4; ++i) acc[j][i] = 0.f;

    for (int kc = 0; kc < 256; kc += 16) {
        // ---- Fs: coalesced over bc2 ----
        {
            int bc2l = t & 63;
            int kq   = t >> 6;      // 0..3
#pragma unroll
            for (int j = 0; j < 4; ++j) {
                int kk = kq * 4 + j;
                int k  = kc + kk;
                float v = 0.f;
                if (k < NLAT) v = f[((size_t)m * NLAT + k) * 512 + bc2tile + bc2l];
                Fs[kk][bc2l] = v;
            }
        }
        // ---- Ws: weights[m][l][k] = pct * w, coalesced over k ----
        {
            int kk = t & 15;
            int lq = t >> 4;        // 0..15
            int k  = kc + kk;
            float wk = (k < NLAT) ? w[k] : 0.f;
#pragma unroll
            for (int j = 0; j < 4; ++j) {
                int ll = lq + j * 16;
                int l  = ltile + ll;
                float v = 0.f;
                if (k < NLAT && l < LMAX)
                    v = pct[((size_t)m * LMAX + l) * NLAT + k] * wk;
                Ws[kk][ll] = v;
            }
        }
        __syncthreads();
#pragma unroll
        for (int kk = 0; kk < 16; ++kk) {
            float a[4], b[4];
#pragma unroll
            for (int i = 0; i < 4; ++i) a[i] = Fs[kk][i * 16 + tx];
            const float4 bv = *(const float4*)&Ws[kk][ty * 4];
            b[0] = bv.x; b[1] = bv.y; b[2] = bv.z; b[3] = bv.w;
#pragma unroll
            for (int j = 0; j < 4; ++j)
#pragma unroll
                for (int i = 0; i < 4; ++i)
                    acc[j][i] += a[i] * b[j];
        }
        __syncthreads();
    }
    // ---- write out[bc][l][m][n] ----
#pragma unroll
    for (int j = 0; j < 4; ++j) {
        int l = ltile + ty * 4 + j;
        if (l < LMAX) {
#pragma unroll
            for (int i = 0; i < 4; ++i) {
                int bc2 = bc2tile + i * 16 + tx;
                int n = bc2 >> 8, bc = bc2 & 255;
                out[(((size_t)bc * LMAX + l) * MMAX + m) * 2 + n] = acc[j][i];
            }
        }
    }
}

extern "C" void kernel_launch(void* const* d_in, const int* in_sizes, int n_in,
                              void* d_out, int out_size, void* d_ws, size_t ws_size,
                              hipStream_t stream) {
    const float* x          = (const float*)d_in[0];
    const float* pct        = (const float*)d_in[1];
    const float* w          = (const float*)d_in[2];
    const int*   ring_index = (const int*)d_in[3];
    const float* ring_mask  = (const float*)d_in[4];
    const float* phase      = (const float*)d_in[5];
    float* out = (float*)d_out;
    float* f   = (float*)d_ws;   // 129*255*512 floats = 67.4 MB

    stageA<<<dim3(NLAT, 4, 5), 256, 0, stream>>>(x, ring_index, ring_mask, phase, f);
    stageB<<<dim3(MMAX, 8, 4), 256, 0, stream>>>(f, pct, w, out);
}

// Round 2
// 207.304 us; speedup vs baseline: 2.9618x; 2.9618x over previous
//
#include <hip/hip_runtime.h>

#define NLAT 255
#define NLON 256
#define NPIX 49152
#define MMAX 129
#define MCS  258      // 2*MMAX
#define NTBL 65       // distinct ring geometries
#define PADA 40       // LDS row pad (u16) for b128-aligned fragment reads

typedef unsigned short ushort_t;
typedef __attribute__((ext_vector_type(8)))  short  bf16x8;
typedef __attribute__((ext_vector_type(4)))  short  short4v;
typedef __attribute__((ext_vector_type(16))) float  f32x16;
typedef __attribute__((ext_vector_type(4)))  float  float4v;

__device__ __forceinline__ ushort_t f2bf(float f) {
    union { float f; unsigned u; } v; v.f = f;
    unsigned r = v.u + 0x7FFFu + ((v.u >> 16) & 1u);   // RTNE
    return (ushort_t)(r >> 16);
}
__device__ __forceinline__ float bf2f(ushort_t h) {
    union { unsigned u; float f; } v; v.u = ((unsigned)h) << 16;
    return v.f;
}

// ---------------- kernel 0: trig table --------------------------------
// Ttab[t][mcs][p] bf16, mask baked in. t = distinct ring geometry.
__global__ __launch_bounds__(256) void trigK(const float* __restrict__ phase,
                                             const float* __restrict__ mask,
                                             ushort_t* __restrict__ Ttab) {
    const int tt  = blockIdx.x;          // 0..64
    const int mcs = blockIdx.y;          // 0..257
    const int p   = threadIdx.x;         // 0..255
    const int r   = (tt < 63) ? tt : (tt == 63 ? 63 : 64);
    float ph = phase[r * NLON + p];
    float mk = mask[r * NLON + p];
    float fm = (float)(mcs >> 1);
    float s, c;
    __sincosf(ph * fm, &s, &c);
    float val = (mcs & 1) ? (-s * mk) : (c * mk);
    Ttab[((size_t)tt * MCS + mcs) * NLON + p] = f2bf(val);
}

// ---------------- kernel 1: stage A (ring DFT via MFMA) ----------------
// block: 512 thr (8 waves), tile = 256 bc x 64 mcs, one ring.
// waves: wrow = wid>>1 (bc strip of 64), wcol = wid&1 (mcs strip of 32).
// f1[m][k][bc2] bf16, bc2 = n*256+bc.
__global__ __launch_bounds__(512) void stageA(const float* __restrict__ x,
                                              const int* __restrict__ ring_index,
                                              const ushort_t* __restrict__ Ttab,
                                              ushort_t* __restrict__ f1) {
    __shared__ __align__(16) ushort_t smem[16896];   // 33792 B
    ushort_t* Rs = smem;                 // [256][PADA]
    ushort_t* Ts = smem + 256 * PADA;    // [64][PADA]

    const int c0 = blockIdx.x * 64;      // mcs tile base (0,64,128,192,256)
    const int r  = blockIdx.y;           // ring
    const int i1 = r + 1;
    const int nph = (i1 < 64) ? 4 * i1 : (i1 <= 192 ? 256 : 4 * (256 - i1));
    const int tbl = (i1 < 64) ? r : (i1 <= 192 ? (63 + (((i1 - 63) & 1) ^ 1)) : 254 - r);
    const int base = ring_index[r * NLON];   // ring start pixel

    const int t    = threadIdx.x;
    const int lane = t & 63;
    const int wid  = t >> 6;
    const int wrow = wid >> 1, wcol = wid & 1;
    const int lg   = lane >> 5;          // 0..1
    const int lc   = lane & 31;          // 0..31

    f32x16 acc[2];
#pragma unroll
    for (int i = 0; i < 2; ++i)
#pragma unroll
        for (int q = 0; q < 16; ++q) acc[i][q] = 0.f;

    for (int pc = 0; pc < nph; pc += 32) {
        // ---- Rs fill: gather x (contiguous ring pixels), fp32 -> bf16 ----
        {
            const int ch = t & 7;           // p chunk of 4
            const int p4 = ch * 4;
            const bool ok = (pc + p4) < nph;
#pragma unroll
            for (int it = 0; it < 4; ++it) {
                int bc = (t >> 3) + it * 64;
                float4v v = {0.f, 0.f, 0.f, 0.f};
                if (ok) v = *(const float4v*)(x + (size_t)bc * NPIX + base + pc + p4);
                short4v h;
                h[0] = (short)f2bf(v[0]); h[1] = (short)f2bf(v[1]);
                h[2] = (short)f2bf(v[2]); h[3] = (short)f2bf(v[3]);
                *(short4v*)(Rs + bc * PADA + p4) = h;
            }
        }
        // ---- Ts fill: Ttab rows are [mcs][p] -> direct vector copy ----
        if (t < 256) {
            const int mcsl = t >> 2;        // 0..63
            const int ch   = t & 3;         // p chunk of 8
            const int mcs  = c0 + mcsl;
            bf16x8 v = {0,0,0,0,0,0,0,0};
            if (mcs < MCS)
                v = *(const bf16x8*)(Ttab + ((size_t)tbl * MCS + mcs) * NLON + pc + ch * 8);
            *(bf16x8*)(Ts + mcsl * PADA + ch * 8) = v;
        }
        __syncthreads();
        // ---- MFMA: D[bc][mcs] += R[bc][p] * T[p][mcs] ----
#pragma unroll
        for (int ks = 0; ks < 2; ++ks) {
            bf16x8 b = *(const bf16x8*)(Ts + (wcol * 32 + lc) * PADA + ks * 16 + lg * 8);
#pragma unroll
            for (int i = 0; i < 2; ++i) {
                bf16x8 a = *(const bf16x8*)(Rs + (wrow * 64 + i * 32 + lc) * PADA + ks * 16 + lg * 8);
                acc[i] = __builtin_amdgcn_mfma_f32_32x32x16_bf16(a, b, acc[i], 0, 0, 0);
            }
        }
        __syncthreads();
    }

    // ---- epilogue: stage acc -> LDS [mcs][bc], then coalesced global ----
    ushort_t* Olds = smem;               // [64][264] = 16896 u16 (reuse)
    {
        const int mcsl = wcol * 32 + lc;
#pragma unroll
        for (int i = 0; i < 2; ++i)
#pragma unroll
            for (int q = 0; q < 16; ++q) {
                int bc = wrow * 64 + i * 32 + 4 * lg + (q & 3) + 8 * (q >> 2);
                Olds[mcsl * 264 + bc] = f2bf(acc[i][q]);
            }
    }
    __syncthreads();
#pragma unroll
    for (int it = 0; it < 4; ++it) {
        int row = (t >> 5) + it * 16;    // 0..63
        int ch  = t & 31;                // bc chunk of 8
        int mcs = c0 + row;
        if (mcs < MCS) {
            bf16x8 v = *(const bf16x8*)(Olds + row * 264 + ch * 8);
            int m = mcs >> 1, n = mcs & 1;
            *(bf16x8*)(f1 + ((size_t)m * NLAT + r) * 512 + n * 256 + ch * 8) = v;
        }
    }
}

// ---------------- kernel 2: stage B (Legendre via MFMA) ----------------
// block: 256 thr (4 waves, 2x2), tile 128 bc2 x 128 l, one m.
// A-fragments read directly from global f1 (coalesced u16, L2-backed).
__global__ __launch_bounds__(256) void stageB(const ushort_t* __restrict__ f1,
                                              const float* __restrict__ pct,
                                              const float* __restrict__ w,
                                              ushort_t* __restrict__ otmp) {
    __shared__ __align__(16) ushort_t Ws[128 * PADA];   // 10240 B

    const int bx  = blockIdx.x;
    const int m   = blockIdx.y;
    const int b2t = (bx & 3) * 128;
    const int lt  = (bx >> 2) * 128;

    const int t    = threadIdx.x;
    const int lane = t & 63;
    const int wid  = t >> 6;
    const int wrow = wid >> 1, wcol = wid & 1;
    const int lg   = lane >> 5;
    const int lc   = lane & 31;

    f32x16 acc[2][2];
#pragma unroll
    for (int i = 0; i < 2; ++i)
#pragma unroll
        for (int j = 0; j < 2; ++j)
#pragma unroll
            for (int q = 0; q < 16; ++q) acc[i][j][q] = 0.f;

    for (int kc = 0; kc < 256; kc += 32) {
        // ---- Ws fill: W[l][k] = pct[m][l][k] * w[k], bf16 ----
        {
            const int kl = t & 31;
            const int k  = kc + kl;
            const float wk = (k < NLAT) ? w[k] : 0.f;
#pragma unroll
            for (int it = 0; it < 16; ++it) {
                int lr = (t >> 5) + it * 8;     // 0..127
                int l  = lt + lr;
                float v = 0.f;
                if (l < NLAT && k < NLAT)
                    v = pct[((size_t)m * NLAT + l) * NLAT + k] * wk;
                Ws[lr * PADA + kl] = f2bf(v);
            }
        }
        __syncthreads();
#pragma unroll
        for (int ks = 0; ks < 2; ++ks) {
            bf16x8 b[2];
#pragma unroll
            for (int jj = 0; jj < 2; ++jj)
                b[jj] = *(const bf16x8*)(Ws + (wcol * 64 + jj * 32 + lc) * PADA + ks * 16 + lg * 8);
#pragma unroll
            for (int i = 0; i < 2; ++i) {
                const int bc2 = b2t + wrow * 64 + i * 32 + lc;
                const int kb  = kc + ks * 16 + lg * 8;
                bf16x8 a;
#pragma unroll
                for (int j = 0; j < 8; ++j) {
                    int k = kb + j;
                    a[j] = (k < NLAT) ? (short)f1[((size_t)m * NLAT + k) * 512 + bc2] : (short)0;
                }
#pragma unroll
                for (int jj = 0; jj < 2; ++jj)
                    acc[i][jj] = __builtin_amdgcn_mfma_f32_32x32x16_bf16(a, b[jj], acc[i][jj], 0, 0, 0);
            }
        }
        __syncthreads();
    }
    // ---- store otmp[m][bc2][l] bf16 (32B-chunk coalesced) ----
#pragma unroll
    for (int i = 0; i < 2; ++i)
#pragma unroll
        for (int jj = 0; jj < 2; ++jj) {
            int l = lt + wcol * 64 + jj * 32 + lc;
            if (l < NLAT) {
#pragma unroll
                for (int q = 0; q < 16; ++q) {
                    int bc2 = b2t + wrow * 64 + i * 32 + 4 * lg + (q & 3) + 8 * (q >> 2);
                    otmp[((size_t)m * 512 + bc2) * NLAT + l] = f2bf(acc[i][jj][q]);
                }
            }
        }
}

// ---------------- kernel 3: permute to out[bc][l][m][n] ----------------
__global__ __launch_bounds__(256) void permuteK(const ushort_t* __restrict__ otmp,
                                                float* __restrict__ out) {
    __shared__ ushort_t L[MCS * 66];     // 34056 B
    const int bc = blockIdx.x;
    const int l0 = blockIdx.y * 64;
    const int t  = threadIdx.x;
    const int ll = t & 63;
    const int l  = l0 + ll;
#pragma unroll 4
    for (int it = 0; it < 65; ++it) {
        int mn = (t >> 6) + it * 4;
        if (mn < MCS) {
            int mm = mn >> 1, n = mn & 1;
            ushort_t v = 0;
            if (l < NLAT)
                v = otmp[((size_t)mm * 512 + n * 256 + bc) * NLAT + l];
            L[mn * 66 + ll] = v;
        }
    }
    __syncthreads();
    for (int ll2 = 0; ll2 < 64; ++ll2) {
        int lo = l0 + ll2;
        if (lo >= NLAT) break;
        size_t rowb = ((size_t)bc * NLAT + lo) * MCS;
        out[rowb + t] = bf2f(L[t * 66 + ll2]);
        if (t < 2)
            out[rowb + 256 + t] = bf2f(L[(256 + t) * 66 + ll2]);
    }
}

extern "C" void kernel_launch(void* const* d_in, const int* in_sizes, int n_in,
                              void* d_out, int out_size, void* d_ws, size_t ws_size,
                              hipStream_t stream) {
    const float* x          = (const float*)d_in[0];
    const float* pct        = (const float*)d_in[1];
    const float* w          = (const float*)d_in[2];
    const int*   ring_index = (const int*)d_in[3];
    const float* ring_mask  = (const float*)d_in[4];
    const float* phase      = (const float*)d_in[5];
    float* out = (float*)d_out;

    // ws layout: [f1: 33,680,640 B][region2: Ttab (8.6MB) then otmp (33,680,640 B)]
    ushort_t* f1   = (ushort_t*)d_ws;
    ushort_t* reg2 = (ushort_t*)((char*)d_ws + (size_t)MMAX * NLAT * 512 * 2);
    ushort_t* Ttab = reg2;
    ushort_t* otmp = reg2;

    trigK  <<<dim3(NTBL, MCS), 256, 0, stream>>>(phase, ring_mask, Ttab);
    stageA <<<dim3(5, NLAT),   512, 0, stream>>>(x, ring_index, Ttab, f1);
    stageB <<<dim3(8, MMAX),   256, 0, stream>>>(f1, pct, w, otmp);
    permuteK<<<dim3(256, 4),   256, 0, stream>>>(otmp, out);
}

// Round 3
// 162.918 us; speedup vs baseline: 3.7688x; 1.2724x over previous
//
#include <hip/hip_runtime.h>

#define NLAT 255
#define NLON 256
#define NPIX 49152
#define MMAX 129
#define MCS  258      // 2*MMAX
#define NTBL 65       // distinct ring geometries
#define PADA 40       // stageA LDS row pad (u16)

typedef unsigned short ushort_t;
typedef __attribute__((ext_vector_type(8)))  short  bf16x8;
typedef __attribute__((ext_vector_type(4)))  short  short4v;
typedef __attribute__((ext_vector_type(16))) float  f32x16;
typedef __attribute__((ext_vector_type(4)))  float  float4v;
typedef __attribute__((ext_vector_type(4), aligned(4))) float float4u;  // 4B-aligned vector load

__device__ __forceinline__ ushort_t f2bf(float f) {
    union { float f; unsigned u; } v; v.f = f;
    unsigned r = v.u + 0x7FFFu + ((v.u >> 16) & 1u);   // RTNE
    return (ushort_t)(r >> 16);
}
__device__ __forceinline__ float bf2f(ushort_t h) {
    union { unsigned u; float f; } v; v.u = ((unsigned)h) << 16;
    return v.f;
}

// ---------------- kernel 0: trig table --------------------------------
__global__ __launch_bounds__(256) void trigK(const float* __restrict__ phase,
                                             const float* __restrict__ mask,
                                             ushort_t* __restrict__ Ttab) {
    const int tt  = blockIdx.x;          // 0..64
    const int mcs = blockIdx.y;          // 0..257
    const int p   = threadIdx.x;         // 0..255
    const int r   = (tt < 63) ? tt : (tt == 63 ? 63 : 64);
    float ph = phase[r * NLON + p];
    float mk = mask[r * NLON + p];
    float fm = (float)(mcs >> 1);
    float s, c;
    __sincosf(ph * fm, &s, &c);
    float val = (mcs & 1) ? (-s * mk) : (c * mk);
    Ttab[((size_t)tt * MCS + mcs) * NLON + p] = f2bf(val);
}

// ---------------- kernel 1: stage A (ring DFT via MFMA) ----------------
__global__ __launch_bounds__(512) void stageA(const float* __restrict__ x,
                                              const int* __restrict__ ring_index,
                                              const ushort_t* __restrict__ Ttab,
                                              ushort_t* __restrict__ f1) {
    __shared__ __align__(16) ushort_t smem[16896];   // 33792 B
    ushort_t* Rs = smem;                 // [256][PADA]
    ushort_t* Ts = smem + 256 * PADA;    // [64][PADA]

    const int c0 = blockIdx.x * 64;      // mcs tile base
    const int r  = blockIdx.y;           // ring
    const int i1 = r + 1;
    const int nph = (i1 < 64) ? 4 * i1 : (i1 <= 192 ? 256 : 4 * (256 - i1));
    const int tbl = (i1 < 64) ? r : (i1 <= 192 ? (63 + (((i1 - 63) & 1) ^ 1)) : 254 - r);
    const int base = ring_index[r * NLON];

    const int t    = threadIdx.x;
    const int lane = t & 63;
    const int wid  = t >> 6;
    const int wrow = wid >> 1, wcol = wid & 1;
    const int lg   = lane >> 5;
    const int lc   = lane & 31;

    f32x16 acc[2];
#pragma unroll
    for (int i = 0; i < 2; ++i)
#pragma unroll
        for (int q = 0; q < 16; ++q) acc[i][q] = 0.f;

    for (int pc = 0; pc < nph; pc += 32) {
        {
            const int ch = t & 7;
            const int p4 = ch * 4;
            const bool ok = (pc + p4) < nph;
#pragma unroll
            for (int it = 0; it < 4; ++it) {
                int bc = (t >> 3) + it * 64;
                float4v v = {0.f, 0.f, 0.f, 0.f};
                if (ok) v = *(const float4v*)(x + (size_t)bc * NPIX + base + pc + p4);
                short4v h;
                h[0] = (short)f2bf(v[0]); h[1] = (short)f2bf(v[1]);
                h[2] = (short)f2bf(v[2]); h[3] = (short)f2bf(v[3]);
                *(short4v*)(Rs + bc * PADA + p4) = h;
            }
        }
        if (t < 256) {
            const int mcsl = t >> 2;
            const int ch   = t & 3;
            const int mcs  = c0 + mcsl;
            bf16x8 v = {0,0,0,0,0,0,0,0};
            if (mcs < MCS)
                v = *(const bf16x8*)(Ttab + ((size_t)tbl * MCS + mcs) * NLON + pc + ch * 8);
            *(bf16x8*)(Ts + mcsl * PADA + ch * 8) = v;
        }
        __syncthreads();
#pragma unroll
        for (int ks = 0; ks < 2; ++ks) {
            bf16x8 b = *(const bf16x8*)(Ts + (wcol * 32 + lc) * PADA + ks * 16 + lg * 8);
#pragma unroll
            for (int i = 0; i < 2; ++i) {
                bf16x8 a = *(const bf16x8*)(Rs + (wrow * 64 + i * 32 + lc) * PADA + ks * 16 + lg * 8);
                acc[i] = __builtin_amdgcn_mfma_f32_32x32x16_bf16(a, b, acc[i], 0, 0, 0);
            }
        }
        __syncthreads();
    }

    ushort_t* Olds = smem;               // [64][264]
    {
        const int mcsl = wcol * 32 + lc;
#pragma unroll
        for (int i = 0; i < 2; ++i)
#pragma unroll
            for (int q = 0; q < 16; ++q) {
                int bc = wrow * 64 + i * 32 + 4 * lg + (q & 3) + 8 * (q >> 2);
                Olds[mcsl * 264 + bc] = f2bf(acc[i][q]);
            }
    }
    __syncthreads();
#pragma unroll
    for (int it = 0; it < 4; ++it) {
        int row = (t >> 5) + it * 16;
        int ch  = t & 31;
        int mcs = c0 + row;
        if (mcs < MCS) {
            bf16x8 v = *(const bf16x8*)(Olds + row * 264 + ch * 8);
            int m = mcs >> 1, n = mcs & 1;
            *(bf16x8*)(f1 + ((size_t)m * NLAT + r) * 512 + n * 256 + ch * 8) = v;
        }
    }
}

// ---------------- kernel 2: transpose f1[m][k][bc2] -> f1t[m][bc2][k256] ----
__global__ __launch_bounds__(256) void transK(const ushort_t* __restrict__ f1,
                                              ushort_t* __restrict__ f1t, int m0) {
    __shared__ __align__(16) ushort_t T[64][72];
    const int m  = m0 + blockIdx.x;
    const int k0 = blockIdx.y * 64;
    const int b0 = blockIdx.z * 64;
    const int t  = threadIdx.x;
#pragma unroll
    for (int it = 0; it < 2; ++it) {
        int id = t + it * 256;
        int kk = id >> 3, ch = id & 7;
        int k  = k0 + kk;
        bf16x8 v = {0,0,0,0,0,0,0,0};
        if (k < NLAT)
            v = *(const bf16x8*)(f1 + ((size_t)m * NLAT + k) * 512 + b0 + ch * 8);
        *(bf16x8*)(&T[kk][ch * 8]) = v;
    }
    __syncthreads();
#pragma unroll
    for (int it = 0; it < 2; ++it) {
        int id  = t + it * 256;
        int bb  = id & 63, ch8 = id >> 6;   // wave covers all 64 bb -> 2-way banks
        bf16x8 v;
#pragma unroll
        for (int j = 0; j < 8; ++j) v[j] = T[ch8 * 8 + j][bb];
        *(bf16x8*)(f1t + ((size_t)m * 512 + b0 + bb) * 256 + k0 + ch8 * 8) = v;
    }
}

// ---------------- kernel 3: stage B (Legendre via MFMA) ----------------
// 256 thr (4 waves 2x2), tile 128 bc2 x 128 l, one m per 8 blocks (same XCD).
__global__ __launch_bounds__(256) void stageB(const ushort_t* __restrict__ f1t,
                                              const float* __restrict__ pct,
                                              const float* __restrict__ w,
                                              ushort_t* __restrict__ otmp,
                                              int mbase) {
    __shared__ __align__(16) ushort_t SB[17408];     // 34816 B (Ws dbuf | Es alias)
    ushort_t* WsB = SB;                              // [2][128*40]
    ushort_t* EsB = SB;                              // [128*136]

    int m, sub;
    if (mbase == 0) { m = blockIdx.x >> 3; sub = blockIdx.x & 7; }
    else {
        int id = blockIdx.x;
        m = mbase + ((id >> 6) << 3) + (id & 7);     // same-m blocks: ids 8 apart, same XCD
        sub = (id >> 3) & 7;
        if (m >= MMAX) return;
    }
    const int b2t = (sub & 3) * 128;
    const int lt  = (sub >> 2) * 128;

    const int t    = threadIdx.x;
    const int lane = t & 63;
    const int wid  = t >> 6;
    const int wrow = wid >> 1, wcol = wid & 1;
    const int lg   = lane >> 5, lc = lane & 31;

    const int flr   = t >> 1;          // fill: l-row 0..127
    const int fhalf = t & 1;           // fill: k half (16 k)
    const int gl    = lt + flr;

    f32x16 acc[2][2];
#pragma unroll
    for (int i = 0; i < 2; ++i)
#pragma unroll
        for (int j = 0; j < 2; ++j)
#pragma unroll
            for (int q = 0; q < 16; ++q) acc[i][j][q] = 0.f;

    const ushort_t* arow0 = f1t + ((size_t)m * 512 + b2t + wrow * 64 + lc) * 256;
    const ushort_t* arow1 = arow0 + 32 * 256;

    auto fill = [&](ushort_t* buf, int kc) {
        const int kb = kc + fhalf * 16;
        float vals[16];
        if (gl < NLAT) {
            const float* src = pct + ((size_t)m * NLAT + gl) * NLAT + kb;
#pragma unroll
            for (int c = 0; c < 4; ++c) {
                int k4 = kb + c * 4;
                if (k4 + 4 <= NLAT) {
                    float4u pv = *(const float4u*)(src + c * 4);
                    float4v wv = *(const float4v*)(w + k4);
#pragma unroll
                    for (int j = 0; j < 4; ++j) vals[c * 4 + j] = pv[j] * wv[j];
                } else {
#pragma unroll
                    for (int j = 0; j < 4; ++j) {
                        int k = k4 + j;
                        vals[c * 4 + j] = (k < NLAT) ? src[c * 4 + j] * w[k] : 0.f;
                    }
                }
            }
        } else {
#pragma unroll
            for (int c = 0; c < 16; ++c) vals[c] = 0.f;
        }
        ushort_t* dst = buf + flr * 40 + fhalf * 16;
#pragma unroll
        for (int c = 0; c < 4; ++c) {
            short4v h;
            h[0] = (short)f2bf(vals[c * 4 + 0]);
            h[1] = (short)f2bf(vals[c * 4 + 1]);
            h[2] = (short)f2bf(vals[c * 4 + 2]);
            h[3] = (short)f2bf(vals[c * 4 + 3]);
            *(short4v*)(dst + c * 4) = h;
        }
    };

    fill(WsB, 0);
    __syncthreads();
    int buf = 0;
    for (int kc = 0; kc < 256; kc += 32, buf ^= 1) {
        if (kc + 32 < 256) fill(WsB + (buf ^ 1) * 5120, kc + 32);
        const ushort_t* W = WsB + buf * 5120;
#pragma unroll
        for (int ks = 0; ks < 2; ++ks) {
            const int kb = kc + ks * 16 + lg * 8;
            bf16x8 b0 = *(const bf16x8*)(W + (wcol * 64 + lc) * 40 + ks * 16 + lg * 8);
            bf16x8 b1 = *(const bf16x8*)(W + (wcol * 64 + 32 + lc) * 40 + ks * 16 + lg * 8);
            bf16x8 a0 = *(const bf16x8*)(arow0 + kb);
            bf16x8 a1 = *(const bf16x8*)(arow1 + kb);
            acc[0][0] = __builtin_amdgcn_mfma_f32_32x32x16_bf16(a0, b0, acc[0][0], 0, 0, 0);
            acc[0][1] = __builtin_amdgcn_mfma_f32_32x32x16_bf16(a0, b1, acc[0][1], 0, 0, 0);
            acc[1][0] = __builtin_amdgcn_mfma_f32_32x32x16_bf16(a1, b0, acc[1][0], 0, 0, 0);
            acc[1][1] = __builtin_amdgcn_mfma_f32_32x32x16_bf16(a1, b1, acc[1][1], 0, 0, 0);
        }
        __syncthreads();
    }

    // epilogue: acc -> Es[bc2_local][l_local] -> coalesced otmp rows
#pragma unroll
    for (int i = 0; i < 2; ++i)
#pragma unroll
        for (int jj = 0; jj < 2; ++jj) {
            int ll = wcol * 64 + jj * 32 + lc;
#pragma unroll
            for (int q = 0; q < 16; ++q) {
                int bl = wrow * 64 + i * 32 + 4 * lg + (q & 3) + 8 * (q >> 2);
                EsB[bl * 136 + ll] = f2bf(acc[i][jj][q]);
            }
        }
    __syncthreads();
#pragma unroll
    for (int it = 0; it < 8; ++it) {
        int id2 = t + it * 256;
        int row = id2 >> 4, ch = id2 & 15;
        bf16x8 v = *(const bf16x8*)(EsB + row * 136 + ch * 8);
        *(bf16x8*)(otmp + (((size_t)m * 512 + b2t + row) << 8) + lt + ch * 8) = v;
    }
}

// ---------------- kernel 4: permute to out[bc][l][m][n] ----------------
__global__ __launch_bounds__(256) void permuteK(const ushort_t* __restrict__ otmp,
                                                float* __restrict__ out) {
    __shared__ ushort_t L[MCS * 66];
    const int bc = blockIdx.x;
    const int l0 = blockIdx.y * 64;
    const int t  = threadIdx.x;
    const int ll = t & 63;
    const int l  = l0 + ll;
#pragma unroll 4
    for (int it = 0; it < 65; ++it) {
        int mn = (t >> 6) + it * 4;
        if (mn < MCS) {
            int mm = mn >> 1, n = mn & 1;
            ushort_t v = 0;
            if (l < NLAT)
                v = otmp[(((size_t)mm * 512 + n * 256 + bc) << 8) + l];
            L[mn * 66 + ll] = v;
        }
    }
    __syncthreads();
    for (int ll2 = 0; ll2 < 64; ++ll2) {
        int lo = l0 + ll2;
        if (lo >= NLAT) break;
        size_t rowb = ((size_t)bc * NLAT + lo) * MCS;
        out[rowb + t] = bf2f(L[t * 66 + ll2]);
        if (t < 2)
            out[rowb + 256 + t] = bf2f(L[(256 + t) * 66 + ll2]);
    }
}

extern "C" void kernel_launch(void* const* d_in, const int* in_sizes, int n_in,
                              void* d_out, int out_size, void* d_ws, size_t ws_size,
                              hipStream_t stream) {
    const float* x          = (const float*)d_in[0];
    const float* pct        = (const float*)d_in[1];
    const float* w          = (const float*)d_in[2];
    const int*   ring_index = (const int*)d_in[3];
    const float* ring_mask  = (const float*)d_in[4];
    const float* phase      = (const float*)d_in[5];
    float* out = (float*)d_out;

    // ws choreography (total exactly 67,368,960 B):
    //   f1   @ 0          [129][255][512] u16 = 33,684,480 B
    //   Ttab @ 33,684,480 [65][258][256]  u16 =  8,586,240 B (dead after stageA)
    //   f1t  @ 33,552,384 [129][512][256] u16 = 33,816,576 B (overlaps f1[m=128][k>=126]
    //                                            and Ttab; 2-phase transK makes it safe)
    //   otmp @ 0          [129][512][256] u16 = 33,816,576 B (overlaps f1t[m<2] head;
    //                                            2-phase stageB makes it safe)
    char* wsb = (char*)d_ws;
    ushort_t* f1   = (ushort_t*)wsb;
    ushort_t* Ttab = (ushort_t*)(wsb + 33684480);
    ushort_t* f1t  = (ushort_t*)(wsb + 33552384);
    ushort_t* otmp = (ushort_t*)wsb;

    trigK   <<<dim3(NTBL, MCS), 256, 0, stream>>>(phase, ring_mask, Ttab);
    stageA  <<<dim3(5, NLAT),   512, 0, stream>>>(x, ring_index, Ttab, f1);
    transK  <<<dim3(1, 4, 8),   256, 0, stream>>>(f1, f1t, 128);  // m=128 first (f1 tail consumed)
    transK  <<<dim3(128, 4, 8), 256, 0, stream>>>(f1, f1t, 0);    // m=0..127
    stageB  <<<dim3(16),        256, 0, stream>>>(f1t, pct, w, otmp, 0);  // m=0,1 (f1t head consumed)
    stageB  <<<dim3(1024),      256, 0, stream>>>(f1t, pct, w, otmp, 2);  // m=2..128
    permuteK<<<dim3(256, 4),    256, 0, stream>>>(otmp, out);
}